// Round 3
// baseline (19998.759 us; speedup 1.0000x reference)
//
#include <hip/hip_runtime.h>
#include <math.h>

#define NN 256
#define TT 30
#define FF 128
#define NB 4

static constexpr float INV = 0.08838834764831845f; // 1/sqrt(128)

// ---------------------------------------------------------------------------
// init_kernel: copy x into both ping-pong buffers (observed entries never
// change afterwards; pred only rewrites mask==0 rows).
// ---------------------------------------------------------------------------
__global__ __launch_bounds__(256) void init_kernel(
    const float4* __restrict__ in, float4* __restrict__ a,
    float4* __restrict__ bb, int n4) {
  for (int i = blockIdx.x * 256 + threadIdx.x; i < n4; i += gridDim.x * 256) {
    float4 v = in[i];
    a[i] = v;
    bb[i] = v;
  }
}

// ---------------------------------------------------------------------------
// gate_kernel: per (b,n): A = softmax(X X^T * inv) over s; gate[b,t,n] = A@wl
// grid (NN, NB), 128 threads
// ---------------------------------------------------------------------------
__global__ __launch_bounds__(128) void gate_kernel(
    const float* __restrict__ x, const float* __restrict__ wlin,
    float* __restrict__ gate) {
  int n = blockIdx.x, b = blockIdx.y;
  __shared__ float Xs[TT * 132];
  __shared__ float A[TT * 33];
  __shared__ float wl[32];
  int tid = threadIdx.x;
  const float* xp = x + ((size_t)(b * NN + n)) * TT * FF;
  for (int idx = tid; idx < TT * 32; idx += 128) {
    int t = idx >> 5, q = idx & 31;
    *(float4*)&Xs[t * 132 + q * 4] = *(const float4*)&xp[t * 128 + q * 4];
  }
  if (tid < TT) wl[tid] = wlin[tid];
  __syncthreads();
  int t = tid >> 2, sg = tid & 3;
  if (t < TT) {
    float a[8];
    #pragma unroll
    for (int u = 0; u < 8; ++u) a[u] = 0.f;
    int smax = TT - sg * 8;  // 8,8,8,6
    for (int q = 0; q < 32; ++q) {
      float4 av = *(const float4*)&Xs[t * 132 + q * 4];
      #pragma unroll
      for (int u = 0; u < 8; ++u) {
        if (u < smax) {
          float4 bv = *(const float4*)&Xs[(sg * 8 + u) * 132 + q * 4];
          a[u] += av.x * bv.x + av.y * bv.y + av.z * bv.z + av.w * bv.w;
        }
      }
    }
    #pragma unroll
    for (int u = 0; u < 8; ++u)
      if (u < smax) A[t * 33 + sg * 8 + u] = a[u] * INV;
  }
  __syncthreads();
  if (tid < TT) {
    float mx = -1e30f;
    #pragma unroll
    for (int s = 0; s < TT; ++s) mx = fmaxf(mx, A[tid * 33 + s]);
    float sum = 0.f, g = 0.f;
    #pragma unroll
    for (int s = 0; s < TT; ++s) {
      float e = expf(A[tid * 33 + s] - mx);
      sum += e;
      g += e * wl[s];
    }
    gate[((size_t)b * TT + tid) * NN + n] = g / sum;
  }
}

// ---------------------------------------------------------------------------
// score_kernel:
//  mode 0: P[n,m] = phase[b,t+1,n,m] * softmax_m(inv*<x[n,t],x[m,t+1]>) * gate
//  mode 1: P[n,m] = phase[b,t,n,m] * sym_adj[n,m] * softmax_m(...) * inv
//  grid (4, T-1 or T, NB), 256 threads; block = 64 rows x 256 cols.
//  Epilogue transposes through LDS so P stores are 1KB-contiguous per wave.
// ---------------------------------------------------------------------------
__global__ __launch_bounds__(256) void score_kernel(
    const float* __restrict__ x, const float* __restrict__ phase,
    const float* __restrict__ gate, const float* __restrict__ symadj,
    float* __restrict__ P, int mode) {
  int ntile = blockIdx.x, t = blockIdx.y, b = blockIdx.z;
  int tq = t, tk = mode ? t : t + 1, pt = mode ? t : t + 1;
  __shared__ union {
    struct { float Xn[64 * 36]; float Xm[256 * 36]; } c;
    float L[16 * 264];
  } sm;
  int tid = threadIdx.x;
  int tr = tid >> 4, tc = tid & 15;
  int n0 = ntile * 64;
  float acc[4][16];
  #pragma unroll
  for (int r = 0; r < 4; ++r)
    #pragma unroll
    for (int j = 0; j < 16; ++j) acc[r][j] = 0.f;

  for (int ftile = 0; ftile < 4; ++ftile) {
    __syncthreads();
    for (int idx = tid; idx < 256 * 8; idx += 256) {
      int row = idx >> 3, q = idx & 7;
      *(float4*)&sm.c.Xm[row * 36 + q * 4] =
          *(const float4*)(x + (((size_t)(b * NN + row)) * TT + tk) * FF + ftile * 32 + q * 4);
    }
    for (int idx = tid; idx < 64 * 8; idx += 256) {
      int row = idx >> 3, q = idx & 7;
      *(float4*)&sm.c.Xn[row * 36 + q * 4] =
          *(const float4*)(x + (((size_t)(b * NN + n0 + row)) * TT + tq) * FF + ftile * 32 + q * 4);
    }
    __syncthreads();
    #pragma unroll
    for (int f = 0; f < 32; f += 4) {
      float4 a0 = *(const float4*)&sm.c.Xn[(tr * 4 + 0) * 36 + f];
      float4 a1 = *(const float4*)&sm.c.Xn[(tr * 4 + 1) * 36 + f];
      float4 a2 = *(const float4*)&sm.c.Xn[(tr * 4 + 2) * 36 + f];
      float4 a3 = *(const float4*)&sm.c.Xn[(tr * 4 + 3) * 36 + f];
      #pragma unroll
      for (int j = 0; j < 16; ++j) {
        float4 bv = *(const float4*)&sm.c.Xm[(j * 16 + tc) * 36 + f];
        acc[0][j] += a0.x * bv.x + a0.y * bv.y + a0.z * bv.z + a0.w * bv.w;
        acc[1][j] += a1.x * bv.x + a1.y * bv.y + a1.z * bv.z + a1.w * bv.w;
        acc[2][j] += a2.x * bv.x + a2.y * bv.y + a2.z * bv.z + a2.w * bv.w;
        acc[3][j] += a3.x * bv.x + a3.y * bv.y + a3.z * bv.z + a3.w * bv.w;
      }
    }
  }

  // softmax over m per row; fold row-scale (gate or inv) into values
  float rowscale[4];
  #pragma unroll
  for (int r = 0; r < 4; ++r) {
    int n = n0 + tr * 4 + r;
    float mx = -1e30f;
    #pragma unroll
    for (int j = 0; j < 16; ++j) {
      acc[r][j] *= INV;
      mx = fmaxf(mx, acc[r][j]);
    }
    #pragma unroll
    for (int d = 1; d < 16; d <<= 1) mx = fmaxf(mx, __shfl_xor(mx, d));
    float sum = 0.f;
    #pragma unroll
    for (int j = 0; j < 16; ++j) {
      acc[r][j] = expf(acc[r][j] - mx);
      sum += acc[r][j];
    }
    #pragma unroll
    for (int d = 1; d < 16; d <<= 1) sum += __shfl_xor(sum, d);
    float rs = 1.f / sum;
    rowscale[r] = mode ? rs * INV : gate[((size_t)b * TT + pt) * NN + n] * rs;
  }

  // transposed epilogue: fully unrolled (acc must stay in registers!)
  __syncthreads();
  #pragma unroll
  for (int r = 0; r < 4; ++r) {
    #pragma unroll
    for (int j = 0; j < 16; ++j)
      sm.L[tr * 264 + j * 16 + tc] = acc[r][j] * rowscale[r];
    __syncthreads();
    #pragma unroll
    for (int k = 0; k < 4; ++k) {
      int lrow = 4 * k + (tid >> 6);
      int col = (tid & 63) * 4;
      float4 v = *(const float4*)&sm.L[lrow * 264 + col];
      int n = n0 + lrow * 4 + r;
      float4 pv = *(const float4*)(phase + ((((size_t)(b * TT + pt)) * NN + n)) * NN + col);
      float4 o;
      o.x = v.x * pv.x; o.y = v.y * pv.y; o.z = v.z * pv.z; o.w = v.w * pv.w;
      if (mode) {
        float4 sv = *(const float4*)(symadj + (size_t)n * NN + col);
        o.x *= sv.x; o.y *= sv.y; o.z *= sv.z; o.w *= sv.w;
      }
      *(float4*)(P + (((size_t)(b * TT + t)) * NN + n) * NN + col) = o;
    }
    __syncthreads();
  }
}

// ---------------------------------------------------------------------------
// pred_kernel: out[n,f] = sum_m P[m,n] * x[b,m,t,f]   (P^T X)
//  mode 0: write ONLY missing rows (mask==0) of x_new slice t+1
//  mode 1: write agg[b,t,n,f]
// ---------------------------------------------------------------------------
__global__ __launch_bounds__(256) void pred_kernel(
    const float* __restrict__ x, const float* __restrict__ P,
    const int* __restrict__ mask, float* __restrict__ xout, int mode) {
  int ntile = blockIdx.x, t = blockIdx.y, b = blockIdx.z;
  __shared__ union {
    struct { float Pt[64 * 64]; float Xt[64 * 128]; } c;
    float L[16 * 136];
  } sm;
  int tid = threadIdx.x;
  int tr = tid >> 4, tc = tid & 15;
  int n0 = ntile * 64;
  float acc[4][8];
  #pragma unroll
  for (int r = 0; r < 4; ++r)
    #pragma unroll
    for (int q = 0; q < 8; ++q) acc[r][q] = 0.f;

  for (int mt = 0; mt < 4; ++mt) {
    __syncthreads();
    for (int idx = tid; idx < 64 * 16; idx += 256) {
      int row = idx >> 4, c4 = (idx & 15) * 4;
      *(float4*)&sm.c.Pt[row * 64 + c4] =
          *(const float4*)(P + (((size_t)(b * TT + t)) * NN + mt * 64 + row) * NN + n0 + c4);
    }
    for (int idx = tid; idx < 64 * 32; idx += 256) {
      int row = idx >> 5, q = idx & 31;
      *(float4*)&sm.c.Xt[row * 128 + q * 4] =
          *(const float4*)(x + (((size_t)(b * NN + mt * 64 + row)) * TT + t) * FF + q * 4);
    }
    __syncthreads();
    for (int i = 0; i < 64; ++i) {
      float4 pv = *(const float4*)&sm.c.Pt[i * 64 + tr * 4];
      #pragma unroll
      for (int q = 0; q < 8; ++q) {
        float xv = sm.c.Xt[i * 128 + q * 16 + tc];
        acc[0][q] += pv.x * xv;
        acc[1][q] += pv.y * xv;
        acc[2][q] += pv.z * xv;
        acc[3][q] += pv.w * xv;
      }
    }
  }

  __syncthreads();
  #pragma unroll
  for (int r = 0; r < 4; ++r) {
    #pragma unroll
    for (int q = 0; q < 8; ++q)
      sm.L[tr * 136 + q * 16 + tc] = acc[r][q];
    __syncthreads();
    #pragma unroll
    for (int k = 0; k < 2; ++k) {
      int lrow = 8 * k + (tid >> 5);
      int col = (tid & 31) * 4;
      float4 v = *(const float4*)&sm.L[lrow * 136 + col];
      int n = n0 + lrow * 4 + r;
      if (mode == 0) {
        int tw = t + 1;
        if (mask[n * TT + tw] == 0)
          *(float4*)(xout + (((size_t)(b * NN + n)) * TT + tw) * FF + col) = v;
      } else {
        *(float4*)(xout + (((size_t)(b * TT + t)) * NN + n) * FF + col) = v;
      }
    }
    __syncthreads();
  }
}

// ---------------------------------------------------------------------------
// theta_kernel: out[b,n,t,o] = relu(sum_f agg[b,t,n,f] * Wt[o,f])
// ---------------------------------------------------------------------------
__global__ __launch_bounds__(256) void theta_kernel(
    const float* __restrict__ agg, const float* __restrict__ Wt,
    float* __restrict__ out) {
  int ntile = blockIdx.x, t = blockIdx.y, b = blockIdx.z;
  __shared__ union {
    struct { float Ag[64 * 68]; float Ws[128 * 68]; } c;
    float L[16 * 136];
  } sm;
  int tid = threadIdx.x;
  int tr = tid >> 4, tc = tid & 15;
  int n0 = ntile * 64;
  float acc[4][8];
  #pragma unroll
  for (int r = 0; r < 4; ++r)
    #pragma unroll
    for (int q = 0; q < 8; ++q) acc[r][q] = 0.f;

  for (int ft = 0; ft < 2; ++ft) {
    __syncthreads();
    for (int idx = tid; idx < 64 * 16; idx += 256) {
      int row = idx >> 4, c4 = (idx & 15) * 4;
      *(float4*)&sm.c.Ag[row * 68 + c4] =
          *(const float4*)(agg + (((size_t)(b * TT + t)) * NN + n0 + row) * FF + ft * 64 + c4);
    }
    for (int idx = tid; idx < 128 * 16; idx += 256) {
      int row = idx >> 4, c4 = (idx & 15) * 4;
      *(float4*)&sm.c.Ws[row * 68 + c4] =
          *(const float4*)(Wt + (size_t)row * FF + ft * 64 + c4);
    }
    __syncthreads();
    #pragma unroll
    for (int f = 0; f < 64; f += 4) {
      float4 a0 = *(const float4*)&sm.c.Ag[(tr * 4 + 0) * 68 + f];
      float4 a1 = *(const float4*)&sm.c.Ag[(tr * 4 + 1) * 68 + f];
      float4 a2 = *(const float4*)&sm.c.Ag[(tr * 4 + 2) * 68 + f];
      float4 a3 = *(const float4*)&sm.c.Ag[(tr * 4 + 3) * 68 + f];
      #pragma unroll
      for (int q = 0; q < 8; ++q) {
        float4 wv = *(const float4*)&sm.c.Ws[(q * 16 + tc) * 68 + f];
        acc[0][q] += a0.x * wv.x + a0.y * wv.y + a0.z * wv.z + a0.w * wv.w;
        acc[1][q] += a1.x * wv.x + a1.y * wv.y + a1.z * wv.z + a1.w * wv.w;
        acc[2][q] += a2.x * wv.x + a2.y * wv.y + a2.z * wv.z + a2.w * wv.w;
        acc[3][q] += a3.x * wv.x + a3.y * wv.y + a3.z * wv.z + a3.w * wv.w;
      }
    }
  }

  __syncthreads();
  #pragma unroll
  for (int r = 0; r < 4; ++r) {
    #pragma unroll
    for (int q = 0; q < 8; ++q)
      sm.L[tr * 136 + q * 16 + tc] = fmaxf(acc[r][q], 0.f);
    __syncthreads();
    #pragma unroll
    for (int k = 0; k < 2; ++k) {
      int lrow = 8 * k + (tid >> 5);
      int col = (tid & 31) * 4;
      float4 v = *(const float4*)&sm.L[lrow * 136 + col];
      int n = n0 + lrow * 4 + r;
      *(float4*)(out + (((size_t)(b * NN + n)) * TT + t) * FF + col) = v;
    }
    __syncthreads();
  }
}

// ---------------------------------------------------------------------------
extern "C" void kernel_launch(void* const* d_in, const int* in_sizes, int n_in,
                              void* d_out, int out_size, void* d_ws, size_t ws_size,
                              hipStream_t stream) {
  const float* x = (const float*)d_in[0];
  const float* phase = (const float*)d_in[1];
  const float* symadj = (const float*)d_in[2];
  const int* mask = (const int*)d_in[3];
  const float* Wt = (const float*)d_in[4];
  const float* Wl = (const float*)d_in[5];
  float* out = (float*)d_out;
  float* ws = (float*)d_ws;

  const size_t SX = (size_t)NB * NN * TT * FF;  // 3,932,160 floats
  float* xA = ws;
  float* xB = xA + SX;
  float* gateb = xB + SX;                        // NB*TT*NN floats
  float* Pw = gateb + (size_t)NB * TT * NN;      // NB*TT*NN*NN floats

  init_kernel<<<1024, 256, 0, stream>>>((const float4*)x, (float4*)xA,
                                        (float4*)xB, (int)(SX / 4));

  float* xc = xA;
  float* xn = xB;
  for (int it = 0; it < TT - 1; ++it) {
    gate_kernel<<<dim3(NN, NB), 128, 0, stream>>>(xc, Wl, gateb);
    score_kernel<<<dim3(4, TT - 1, NB), 256, 0, stream>>>(xc, phase, gateb, symadj, Pw, 0);
    pred_kernel<<<dim3(4, TT - 1, NB), 256, 0, stream>>>(xc, Pw, mask, xn, 0);
    float* tmp = xc; xc = xn; xn = tmp;
  }

  float* aggb = xn;  // free buffer
  score_kernel<<<dim3(4, TT, NB), 256, 0, stream>>>(xc, phase, nullptr, symadj, Pw, 1);
  pred_kernel<<<dim3(4, TT, NB), 256, 0, stream>>>(xc, Pw, nullptr, aggb, 1);
  theta_kernel<<<dim3(4, TT, NB), 256, 0, stream>>>(aggb, Wt, out);
}

// Round 4
// 9856.631 us; speedup vs baseline: 2.0290x; 2.0290x over previous
//
#include <hip/hip_runtime.h>
#include <math.h>

#define NN 256
#define TT 30
#define FF 128
#define NB 4

static constexpr float INV = 0.08838834764831845f; // 1/sqrt(128)

// ---------------------------------------------------------------------------
// init_kernel: copy x into both ping-pong buffers (observed entries never
// change afterwards; pred only rewrites mask==0 rows).
// ---------------------------------------------------------------------------
__global__ __launch_bounds__(256) void init_kernel(
    const float4* __restrict__ in, float4* __restrict__ a,
    float4* __restrict__ bb, int n4) {
  for (int i = blockIdx.x * 256 + threadIdx.x; i < n4; i += gridDim.x * 256) {
    float4 v = in[i];
    a[i] = v;
    bb[i] = v;
  }
}

// ---------------------------------------------------------------------------
// gate_kernel: per (b,n): A = softmax(X X^T * inv) over s; gate[b,t,n] = A@wl
// grid (NN, NB), 128 threads
// ---------------------------------------------------------------------------
__global__ __launch_bounds__(128) void gate_kernel(
    const float* __restrict__ x, const float* __restrict__ wlin,
    float* __restrict__ gate) {
  int n = blockIdx.x, b = blockIdx.y;
  __shared__ float Xs[TT * 132];
  __shared__ float A[TT * 33];
  __shared__ float wl[32];
  int tid = threadIdx.x;
  const float* xp = x + ((size_t)(b * NN + n)) * TT * FF;
  for (int idx = tid; idx < TT * 32; idx += 128) {
    int t = idx >> 5, q = idx & 31;
    *(float4*)&Xs[t * 132 + q * 4] = *(const float4*)&xp[t * 128 + q * 4];
  }
  if (tid < TT) wl[tid] = wlin[tid];
  __syncthreads();
  int t = tid >> 2, sg = tid & 3;
  if (t < TT) {
    float a[8];
    #pragma unroll
    for (int u = 0; u < 8; ++u) a[u] = 0.f;
    int smax = TT - sg * 8;  // 8,8,8,6
    for (int q = 0; q < 32; ++q) {
      float4 av = *(const float4*)&Xs[t * 132 + q * 4];
      #pragma unroll
      for (int u = 0; u < 8; ++u) {
        if (u < smax) {
          float4 bv = *(const float4*)&Xs[(sg * 8 + u) * 132 + q * 4];
          a[u] += av.x * bv.x + av.y * bv.y + av.z * bv.z + av.w * bv.w;
        }
      }
    }
    #pragma unroll
    for (int u = 0; u < 8; ++u)
      if (u < smax) A[t * 33 + sg * 8 + u] = a[u] * INV;
  }
  __syncthreads();
  if (tid < TT) {
    float mx = -1e30f;
    #pragma unroll
    for (int s = 0; s < TT; ++s) mx = fmaxf(mx, A[tid * 33 + s]);
    float sum = 0.f, g = 0.f;
    #pragma unroll
    for (int s = 0; s < TT; ++s) {
      float e = expf(A[tid * 33 + s] - mx);
      sum += e;
      g += e * wl[s];
    }
    gate[((size_t)b * TT + tid) * NN + n] = g / sum;
  }
}

// ---------------------------------------------------------------------------
// score_kernel (32 rows x 256 cols per block, acc[2][16] = 32 VGPRs):
//  mode 0: P[n,m] = phase[b,t+1,n,m] * softmax_m(inv*<x[n,t],x[m,t+1]>) * gate
//  mode 1: P[n,m] = phase[b,t,n,m] * sym_adj[n,m] * softmax_m(...) * inv
//  grid (8, T-1 or T, NB), 256 threads.
//  Thread (tr,tc), tr=tid>>4: rows n0+tr*2+{0,1}; cols m=j*16+tc.
// ---------------------------------------------------------------------------
__global__ __launch_bounds__(256) void score_kernel(
    const float* __restrict__ x, const float* __restrict__ phase,
    const float* __restrict__ gate, const float* __restrict__ symadj,
    float* __restrict__ P, int mode) {
  int ntile = blockIdx.x, t = blockIdx.y, b = blockIdx.z;
  int tq = t, tk = mode ? t : t + 1, pt = mode ? t : t + 1;
  __shared__ union {
    struct { float Xn[32 * 36]; float Xm[256 * 36]; } c;
    float L[16 * 264];
  } sm;
  int tid = threadIdx.x;
  int tr = tid >> 4, tc = tid & 15;
  int n0 = ntile * 32;
  float acc[2][16];
  #pragma unroll
  for (int r = 0; r < 2; ++r)
    #pragma unroll
    for (int j = 0; j < 16; ++j) acc[r][j] = 0.f;

  for (int ftile = 0; ftile < 4; ++ftile) {
    __syncthreads();
    for (int idx = tid; idx < 256 * 8; idx += 256) {
      int row = idx >> 3, q = idx & 7;
      *(float4*)&sm.c.Xm[row * 36 + q * 4] =
          *(const float4*)(x + (((size_t)(b * NN + row)) * TT + tk) * FF + ftile * 32 + q * 4);
    }
    {
      int row = tid >> 3, q = tid & 7;
      if (row < 32)
        *(float4*)&sm.c.Xn[row * 36 + q * 4] =
            *(const float4*)(x + (((size_t)(b * NN + n0 + row)) * TT + tq) * FF + ftile * 32 + q * 4);
    }
    __syncthreads();
    #pragma unroll
    for (int f = 0; f < 32; f += 4) {
      float4 a0 = *(const float4*)&sm.c.Xn[(tr * 2 + 0) * 36 + f];
      float4 a1 = *(const float4*)&sm.c.Xn[(tr * 2 + 1) * 36 + f];
      #pragma unroll
      for (int j = 0; j < 16; ++j) {
        float4 bv = *(const float4*)&sm.c.Xm[(j * 16 + tc) * 36 + f];
        acc[0][j] += a0.x * bv.x + a0.y * bv.y + a0.z * bv.z + a0.w * bv.w;
        acc[1][j] += a1.x * bv.x + a1.y * bv.y + a1.z * bv.z + a1.w * bv.w;
      }
    }
  }

  // softmax over m per row; fold row-scale (gate or inv) into values
  float rowscale[2];
  #pragma unroll
  for (int r = 0; r < 2; ++r) {
    int n = n0 + tr * 2 + r;
    float mx = -1e30f;
    #pragma unroll
    for (int j = 0; j < 16; ++j) {
      acc[r][j] *= INV;
      mx = fmaxf(mx, acc[r][j]);
    }
    #pragma unroll
    for (int d = 1; d < 16; d <<= 1) mx = fmaxf(mx, __shfl_xor(mx, d));
    float sum = 0.f;
    #pragma unroll
    for (int j = 0; j < 16; ++j) {
      acc[r][j] = expf(acc[r][j] - mx);
      sum += acc[r][j];
    }
    #pragma unroll
    for (int d = 1; d < 16; d <<= 1) sum += __shfl_xor(sum, d);
    float rs = 1.f / sum;
    rowscale[r] = mode ? rs * INV : gate[((size_t)b * TT + pt) * NN + n] * rs;
  }

  // transposed epilogue: L-row l holds cols of n = n0 + l*2 + r
  __syncthreads();
  #pragma unroll
  for (int r = 0; r < 2; ++r) {
    #pragma unroll
    for (int j = 0; j < 16; ++j)
      sm.L[tr * 264 + j * 16 + tc] = acc[r][j] * rowscale[r];
    __syncthreads();
    #pragma unroll
    for (int k = 0; k < 4; ++k) {
      int lrow = 4 * k + (tid >> 6);
      int col = (tid & 63) * 4;
      float4 v = *(const float4*)&sm.L[lrow * 264 + col];
      int n = n0 + lrow * 2 + r;
      float4 pv = *(const float4*)(phase + ((((size_t)(b * TT + pt)) * NN + n)) * NN + col);
      float4 o;
      o.x = v.x * pv.x; o.y = v.y * pv.y; o.z = v.z * pv.z; o.w = v.w * pv.w;
      if (mode) {
        float4 sv = *(const float4*)(symadj + (size_t)n * NN + col);
        o.x *= sv.x; o.y *= sv.y; o.z *= sv.z; o.w *= sv.w;
      }
      *(float4*)(P + (((size_t)(b * TT + t)) * NN + n) * NN + col) = o;
    }
    __syncthreads();
  }
}

// ---------------------------------------------------------------------------
// pred_kernel: out[n,f] = sum_m P[m,n] * x[b,m,t,f]   (P^T X)
//  mode 0: write ONLY missing rows (mask==0) of x_new slice t+1
//  mode 1: write agg[b,t,n,f]
// ---------------------------------------------------------------------------
__global__ __launch_bounds__(256) void pred_kernel(
    const float* __restrict__ x, const float* __restrict__ P,
    const int* __restrict__ mask, float* __restrict__ xout, int mode) {
  int ntile = blockIdx.x, t = blockIdx.y, b = blockIdx.z;
  __shared__ union {
    struct { float Pt[64 * 64]; float Xt[64 * 128]; } c;
    float L[16 * 136];
  } sm;
  int tid = threadIdx.x;
  int tr = tid >> 4, tc = tid & 15;
  int n0 = ntile * 64;
  float acc[4][8];
  #pragma unroll
  for (int r = 0; r < 4; ++r)
    #pragma unroll
    for (int q = 0; q < 8; ++q) acc[r][q] = 0.f;

  for (int mt = 0; mt < 4; ++mt) {
    __syncthreads();
    for (int idx = tid; idx < 64 * 16; idx += 256) {
      int row = idx >> 4, c4 = (idx & 15) * 4;
      *(float4*)&sm.c.Pt[row * 64 + c4] =
          *(const float4*)(P + (((size_t)(b * TT + t)) * NN + mt * 64 + row) * NN + n0 + c4);
    }
    for (int idx = tid; idx < 64 * 32; idx += 256) {
      int row = idx >> 5, q = idx & 31;
      *(float4*)&sm.c.Xt[row * 128 + q * 4] =
          *(const float4*)(x + (((size_t)(b * NN + mt * 64 + row)) * TT + t) * FF + q * 4);
    }
    __syncthreads();
    for (int i = 0; i < 64; ++i) {
      float4 pv = *(const float4*)&sm.c.Pt[i * 64 + tr * 4];
      #pragma unroll
      for (int q = 0; q < 8; ++q) {
        float xv = sm.c.Xt[i * 128 + q * 16 + tc];
        acc[0][q] += pv.x * xv;
        acc[1][q] += pv.y * xv;
        acc[2][q] += pv.z * xv;
        acc[3][q] += pv.w * xv;
      }
    }
  }

  __syncthreads();
  #pragma unroll
  for (int r = 0; r < 4; ++r) {
    #pragma unroll
    for (int q = 0; q < 8; ++q)
      sm.L[tr * 136 + q * 16 + tc] = acc[r][q];
    __syncthreads();
    #pragma unroll
    for (int k = 0; k < 2; ++k) {
      int lrow = 8 * k + (tid >> 5);
      int col = (tid & 31) * 4;
      float4 v = *(const float4*)&sm.L[lrow * 136 + col];
      int n = n0 + lrow * 4 + r;
      if (mode == 0) {
        int tw = t + 1;
        if (mask[n * TT + tw] == 0)
          *(float4*)(xout + (((size_t)(b * NN + n)) * TT + tw) * FF + col) = v;
      } else {
        *(float4*)(xout + (((size_t)(b * TT + t)) * NN + n) * FF + col) = v;
      }
    }
    __syncthreads();
  }
}

// ---------------------------------------------------------------------------
// theta_kernel: out[b,n,t,o] = relu(sum_f agg[b,t,n,f] * Wt[o,f])
// ---------------------------------------------------------------------------
__global__ __launch_bounds__(256) void theta_kernel(
    const float* __restrict__ agg, const float* __restrict__ Wt,
    float* __restrict__ out) {
  int ntile = blockIdx.x, t = blockIdx.y, b = blockIdx.z;
  __shared__ union {
    struct { float Ag[64 * 68]; float Ws[128 * 68]; } c;
    float L[16 * 136];
  } sm;
  int tid = threadIdx.x;
  int tr = tid >> 4, tc = tid & 15;
  int n0 = ntile * 64;
  float acc[4][8];
  #pragma unroll
  for (int r = 0; r < 4; ++r)
    #pragma unroll
    for (int q = 0; q < 8; ++q) acc[r][q] = 0.f;

  for (int ft = 0; ft < 2; ++ft) {
    __syncthreads();
    for (int idx = tid; idx < 64 * 16; idx += 256) {
      int row = idx >> 4, c4 = (idx & 15) * 4;
      *(float4*)&sm.c.Ag[row * 68 + c4] =
          *(const float4*)(agg + (((size_t)(b * TT + t)) * NN + n0 + row) * FF + ft * 64 + c4);
    }
    for (int idx = tid; idx < 128 * 16; idx += 256) {
      int row = idx >> 4, c4 = (idx & 15) * 4;
      *(float4*)&sm.c.Ws[row * 68 + c4] =
          *(const float4*)(Wt + (size_t)row * FF + ft * 64 + c4);
    }
    __syncthreads();
    #pragma unroll
    for (int f = 0; f < 64; f += 4) {
      float4 a0 = *(const float4*)&sm.c.Ag[(tr * 4 + 0) * 68 + f];
      float4 a1 = *(const float4*)&sm.c.Ag[(tr * 4 + 1) * 68 + f];
      float4 a2 = *(const float4*)&sm.c.Ag[(tr * 4 + 2) * 68 + f];
      float4 a3 = *(const float4*)&sm.c.Ag[(tr * 4 + 3) * 68 + f];
      #pragma unroll
      for (int q = 0; q < 8; ++q) {
        float4 wv = *(const float4*)&sm.c.Ws[(q * 16 + tc) * 68 + f];
        acc[0][q] += a0.x * wv.x + a0.y * wv.y + a0.z * wv.z + a0.w * wv.w;
        acc[1][q] += a1.x * wv.x + a1.y * wv.y + a1.z * wv.z + a1.w * wv.w;
        acc[2][q] += a2.x * wv.x + a2.y * wv.y + a2.z * wv.z + a2.w * wv.w;
        acc[3][q] += a3.x * wv.x + a3.y * wv.y + a3.z * wv.z + a3.w * wv.w;
      }
    }
  }

  __syncthreads();
  #pragma unroll
  for (int r = 0; r < 4; ++r) {
    #pragma unroll
    for (int q = 0; q < 8; ++q)
      sm.L[tr * 136 + q * 16 + tc] = fmaxf(acc[r][q], 0.f);
    __syncthreads();
    #pragma unroll
    for (int k = 0; k < 2; ++k) {
      int lrow = 8 * k + (tid >> 5);
      int col = (tid & 31) * 4;
      float4 v = *(const float4*)&sm.L[lrow * 136 + col];
      int n = n0 + lrow * 4 + r;
      *(float4*)(out + (((size_t)(b * NN + n)) * TT + t) * FF + col) = v;
    }
    __syncthreads();
  }
}

// ---------------------------------------------------------------------------
extern "C" void kernel_launch(void* const* d_in, const int* in_sizes, int n_in,
                              void* d_out, int out_size, void* d_ws, size_t ws_size,
                              hipStream_t stream) {
  const float* x = (const float*)d_in[0];
  const float* phase = (const float*)d_in[1];
  const float* symadj = (const float*)d_in[2];
  const int* mask = (const int*)d_in[3];
  const float* Wt = (const float*)d_in[4];
  const float* Wl = (const float*)d_in[5];
  float* out = (float*)d_out;
  float* ws = (float*)d_ws;

  const size_t SX = (size_t)NB * NN * TT * FF;  // 3,932,160 floats
  float* xA = ws;
  float* xB = xA + SX;
  float* gateb = xB + SX;                        // NB*TT*NN floats
  float* Pw = gateb + (size_t)NB * TT * NN;      // NB*TT*NN*NN floats

  init_kernel<<<1024, 256, 0, stream>>>((const float4*)x, (float4*)xA,
                                        (float4*)xB, (int)(SX / 4));

  float* xc = xA;
  float* xn = xB;
  for (int it = 0; it < TT - 1; ++it) {
    gate_kernel<<<dim3(NN, NB), 128, 0, stream>>>(xc, Wl, gateb);
    score_kernel<<<dim3(8, TT - 1, NB), 256, 0, stream>>>(xc, phase, gateb, symadj, Pw, 0);
    pred_kernel<<<dim3(4, TT - 1, NB), 256, 0, stream>>>(xc, Pw, mask, xn, 0);
    float* tmp = xc; xc = xn; xn = tmp;
  }

  float* aggb = xn;  // free buffer
  score_kernel<<<dim3(8, TT, NB), 256, 0, stream>>>(xc, phase, nullptr, symadj, Pw, 1);
  pred_kernel<<<dim3(4, TT, NB), 256, 0, stream>>>(xc, Pw, nullptr, aggb, 1);
  theta_kernel<<<dim3(4, TT, NB), 256, 0, stream>>>(aggb, Wt, out);
}

// Round 5
// 4414.024 us; speedup vs baseline: 4.5307x; 2.2330x over previous
//
#include <hip/hip_runtime.h>
#include <math.h>

#define NN 256
#define TT 30
#define FF 128
#define NB 4

static constexpr float INV = 0.08838834764831845f; // 1/sqrt(128)

// ---------------------------------------------------------------------------
// init_kernel: copy x into both ping-pong buffers (observed entries never
// change afterwards; pred only rewrites mask==0 rows).
// ---------------------------------------------------------------------------
__global__ __launch_bounds__(256) void init_kernel(
    const float4* __restrict__ in, float4* __restrict__ a,
    float4* __restrict__ bb, int n4) {
  for (int i = blockIdx.x * 256 + threadIdx.x; i < n4; i += gridDim.x * 256) {
    float4 v = in[i];
    a[i] = v;
    bb[i] = v;
  }
}

// ---------------------------------------------------------------------------
// gate_kernel: per (b,n): A = softmax(X X^T * inv) over s; gate[b,t,n] = A@wl
// grid (NN, NB), 128 threads
// ---------------------------------------------------------------------------
__global__ __launch_bounds__(128) void gate_kernel(
    const float* __restrict__ x, const float* __restrict__ wlin,
    float* __restrict__ gate) {
  int n = blockIdx.x, b = blockIdx.y;
  __shared__ float Xs[TT * 132];
  __shared__ float A[TT * 33];
  __shared__ float wl[32];
  int tid = threadIdx.x;
  const float* xp = x + ((size_t)(b * NN + n)) * TT * FF;
  for (int idx = tid; idx < TT * 32; idx += 128) {
    int t = idx >> 5, q = idx & 31;
    *(float4*)&Xs[t * 132 + q * 4] = *(const float4*)&xp[t * 128 + q * 4];
  }
  if (tid < TT) wl[tid] = wlin[tid];
  __syncthreads();
  int t = tid >> 2, sg = tid & 3;
  if (t < TT) {
    float a[8];
    #pragma unroll
    for (int u = 0; u < 8; ++u) a[u] = 0.f;
    int smax = TT - sg * 8;  // 8,8,8,6
    #pragma unroll 1
    for (int q = 0; q < 32; ++q) {
      float4 av = *(const float4*)&Xs[t * 132 + q * 4];
      #pragma unroll
      for (int u = 0; u < 8; ++u) {
        if (u < smax) {
          float4 bv = *(const float4*)&Xs[(sg * 8 + u) * 132 + q * 4];
          a[u] += av.x * bv.x + av.y * bv.y + av.z * bv.z + av.w * bv.w;
        }
      }
    }
    #pragma unroll
    for (int u = 0; u < 8; ++u)
      if (u < smax) A[t * 33 + sg * 8 + u] = a[u] * INV;
  }
  __syncthreads();
  if (tid < TT) {
    float mx = -1e30f;
    #pragma unroll
    for (int s = 0; s < TT; ++s) mx = fmaxf(mx, A[tid * 33 + s]);
    float sum = 0.f, g = 0.f;
    #pragma unroll
    for (int s = 0; s < TT; ++s) {
      float e = expf(A[tid * 33 + s] - mx);
      sum += e;
      g += e * wl[s];
    }
    gate[((size_t)b * TT + tid) * NN + n] = g / sum;
  }
}

// ---------------------------------------------------------------------------
// score_kernel (64 rows x 256 cols per block, acc[4][16]; f-loop unroll 1
// to keep live registers ~190 and avoid spill):
//  mode 0: P[n,m] = phase[b,t+1,n,m] * softmax_m(inv*<x[n,t],x[m,t+1]>) * gate
//  mode 1: P[n,m] = phase[b,t,n,m] * sym_adj[n,m] * softmax_m(...) * inv
//  grid (4, T-1 or T, NB), 256 threads.
// ---------------------------------------------------------------------------
__global__ __launch_bounds__(256) void score_kernel(
    const float* __restrict__ x, const float* __restrict__ phase,
    const float* __restrict__ gate, const float* __restrict__ symadj,
    float* __restrict__ P, int mode) {
  int ntile = blockIdx.x, t = blockIdx.y, b = blockIdx.z;
  int tq = t, tk = mode ? t : t + 1, pt = mode ? t : t + 1;
  __shared__ union {
    struct { float Xn[64 * 36]; float Xm[256 * 36]; } c;
    float L[16 * 264];
  } sm;
  int tid = threadIdx.x;
  int tr = tid >> 4, tc = tid & 15;
  int n0 = ntile * 64;
  float acc[4][16];
  #pragma unroll
  for (int r = 0; r < 4; ++r)
    #pragma unroll
    for (int j = 0; j < 16; ++j) acc[r][j] = 0.f;

  #pragma unroll 1
  for (int ftile = 0; ftile < 4; ++ftile) {
    __syncthreads();
    for (int idx = tid; idx < 256 * 8; idx += 256) {
      int row = idx >> 3, q = idx & 7;
      *(float4*)&sm.c.Xm[row * 36 + q * 4] =
          *(const float4*)(x + (((size_t)(b * NN + row)) * TT + tk) * FF + ftile * 32 + q * 4);
    }
    for (int idx = tid; idx < 64 * 8; idx += 256) {
      int row = idx >> 3, q = idx & 7;
      *(float4*)&sm.c.Xn[row * 36 + q * 4] =
          *(const float4*)(x + (((size_t)(b * NN + n0 + row)) * TT + tq) * FF + ftile * 32 + q * 4);
    }
    __syncthreads();
    #pragma unroll 1
    for (int f = 0; f < 32; f += 4) {
      float4 a0 = *(const float4*)&sm.c.Xn[(tr * 4 + 0) * 36 + f];
      float4 a1 = *(const float4*)&sm.c.Xn[(tr * 4 + 1) * 36 + f];
      float4 a2 = *(const float4*)&sm.c.Xn[(tr * 4 + 2) * 36 + f];
      float4 a3 = *(const float4*)&sm.c.Xn[(tr * 4 + 3) * 36 + f];
      #pragma unroll
      for (int j = 0; j < 16; ++j) {
        float4 bv = *(const float4*)&sm.c.Xm[(j * 16 + tc) * 36 + f];
        acc[0][j] += a0.x * bv.x + a0.y * bv.y + a0.z * bv.z + a0.w * bv.w;
        acc[1][j] += a1.x * bv.x + a1.y * bv.y + a1.z * bv.z + a1.w * bv.w;
        acc[2][j] += a2.x * bv.x + a2.y * bv.y + a2.z * bv.z + a2.w * bv.w;
        acc[3][j] += a3.x * bv.x + a3.y * bv.y + a3.z * bv.z + a3.w * bv.w;
      }
    }
  }

  // softmax over m per row; fold row-scale (gate or inv) into values
  float rowscale[4];
  #pragma unroll
  for (int r = 0; r < 4; ++r) {
    int n = n0 + tr * 4 + r;
    float mx = -1e30f;
    #pragma unroll
    for (int j = 0; j < 16; ++j) {
      acc[r][j] *= INV;
      mx = fmaxf(mx, acc[r][j]);
    }
    #pragma unroll
    for (int d = 1; d < 16; d <<= 1) mx = fmaxf(mx, __shfl_xor(mx, d));
    float sum = 0.f;
    #pragma unroll
    for (int j = 0; j < 16; ++j) {
      acc[r][j] = expf(acc[r][j] - mx);
      sum += acc[r][j];
    }
    #pragma unroll
    for (int d = 1; d < 16; d <<= 1) sum += __shfl_xor(sum, d);
    float rs = 1.f / sum;
    rowscale[r] = mode ? rs * INV : gate[((size_t)b * TT + pt) * NN + n] * rs;
  }

  // transposed epilogue through LDS: coalesced 1KB-per-wave stores
  __syncthreads();
  #pragma unroll 1
  for (int r = 0; r < 4; ++r) {
    #pragma unroll
    for (int j = 0; j < 16; ++j)
      sm.L[tr * 264 + j * 16 + tc] = acc[r][j] * rowscale[r];
    __syncthreads();
    #pragma unroll
    for (int k = 0; k < 4; ++k) {
      int lrow = 4 * k + (tid >> 6);
      int col = (tid & 63) * 4;
      float4 v = *(const float4*)&sm.L[lrow * 264 + col];
      int n = n0 + lrow * 4 + r;
      float4 pv = *(const float4*)(phase + ((((size_t)(b * TT + pt)) * NN + n)) * NN + col);
      float4 o;
      o.x = v.x * pv.x; o.y = v.y * pv.y; o.z = v.z * pv.z; o.w = v.w * pv.w;
      if (mode) {
        float4 sv = *(const float4*)(symadj + (size_t)n * NN + col);
        o.x *= sv.x; o.y *= sv.y; o.z *= sv.z; o.w *= sv.w;
      }
      *(float4*)(P + (((size_t)(b * TT + t)) * NN + n) * NN + col) = o;
    }
    __syncthreads();
  }
}

// ---------------------------------------------------------------------------
// pred_kernel: out[n,f] = sum_m P[m,n] * x[b,m,t,f]   (P^T X)
//  mode 0: write ONLY missing rows (mask==0) of x_new slice t+1
//  mode 1: write agg[b,t,n,f]
// ---------------------------------------------------------------------------
__global__ __launch_bounds__(256) void pred_kernel(
    const float* __restrict__ x, const float* __restrict__ P,
    const int* __restrict__ mask, float* __restrict__ xout, int mode) {
  int ntile = blockIdx.x, t = blockIdx.y, b = blockIdx.z;
  __shared__ union {
    struct { float Pt[64 * 64]; float Xt[64 * 128]; } c;
    float L[16 * 136];
  } sm;
  int tid = threadIdx.x;
  int tr = tid >> 4, tc = tid & 15;
  int n0 = ntile * 64;
  float acc[4][8];
  #pragma unroll
  for (int r = 0; r < 4; ++r)
    #pragma unroll
    for (int q = 0; q < 8; ++q) acc[r][q] = 0.f;

  #pragma unroll 1
  for (int mt = 0; mt < 4; ++mt) {
    __syncthreads();
    for (int idx = tid; idx < 64 * 16; idx += 256) {
      int row = idx >> 4, c4 = (idx & 15) * 4;
      *(float4*)&sm.c.Pt[row * 64 + c4] =
          *(const float4*)(P + (((size_t)(b * TT + t)) * NN + mt * 64 + row) * NN + n0 + c4);
    }
    for (int idx = tid; idx < 64 * 32; idx += 256) {
      int row = idx >> 5, q = idx & 31;
      *(float4*)&sm.c.Xt[row * 128 + q * 4] =
          *(const float4*)(x + (((size_t)(b * NN + mt * 64 + row)) * TT + t) * FF + q * 4);
    }
    __syncthreads();
    #pragma unroll 1
    for (int i = 0; i < 64; ++i) {
      float4 pv = *(const float4*)&sm.c.Pt[i * 64 + tr * 4];
      #pragma unroll
      for (int q = 0; q < 8; ++q) {
        float xv = sm.c.Xt[i * 128 + q * 16 + tc];
        acc[0][q] += pv.x * xv;
        acc[1][q] += pv.y * xv;
        acc[2][q] += pv.z * xv;
        acc[3][q] += pv.w * xv;
      }
    }
  }

  __syncthreads();
  #pragma unroll 1
  for (int r = 0; r < 4; ++r) {
    #pragma unroll
    for (int q = 0; q < 8; ++q)
      sm.L[tr * 136 + q * 16 + tc] = acc[r][q];
    __syncthreads();
    #pragma unroll
    for (int k = 0; k < 2; ++k) {
      int lrow = 8 * k + (tid >> 5);
      int col = (tid & 31) * 4;
      float4 v = *(const float4*)&sm.L[lrow * 136 + col];
      int n = n0 + lrow * 4 + r;
      if (mode == 0) {
        int tw = t + 1;
        if (mask[n * TT + tw] == 0)
          *(float4*)(xout + (((size_t)(b * NN + n)) * TT + tw) * FF + col) = v;
      } else {
        *(float4*)(xout + (((size_t)(b * TT + t)) * NN + n) * FF + col) = v;
      }
    }
    __syncthreads();
  }
}

// ---------------------------------------------------------------------------
// theta_kernel: out[b,n,t,o] = relu(sum_f agg[b,t,n,f] * Wt[o,f])
//  f-loop unroll 1 (was the worst spiller at full unroll).
// ---------------------------------------------------------------------------
__global__ __launch_bounds__(256) void theta_kernel(
    const float* __restrict__ agg, const float* __restrict__ Wt,
    float* __restrict__ out) {
  int ntile = blockIdx.x, t = blockIdx.y, b = blockIdx.z;
  __shared__ union {
    struct { float Ag[64 * 68]; float Ws[128 * 68]; } c;
    float L[16 * 136];
  } sm;
  int tid = threadIdx.x;
  int tr = tid >> 4, tc = tid & 15;
  int n0 = ntile * 64;
  float acc[4][8];
  #pragma unroll
  for (int r = 0; r < 4; ++r)
    #pragma unroll
    for (int q = 0; q < 8; ++q) acc[r][q] = 0.f;

  #pragma unroll 1
  for (int ft = 0; ft < 2; ++ft) {
    __syncthreads();
    for (int idx = tid; idx < 64 * 16; idx += 256) {
      int row = idx >> 4, c4 = (idx & 15) * 4;
      *(float4*)&sm.c.Ag[row * 68 + c4] =
          *(const float4*)(agg + (((size_t)(b * TT + t)) * NN + n0 + row) * FF + ft * 64 + c4);
    }
    for (int idx = tid; idx < 128 * 16; idx += 256) {
      int row = idx >> 4, c4 = (idx & 15) * 4;
      *(float4*)&sm.c.Ws[row * 68 + c4] =
          *(const float4*)(Wt + (size_t)row * FF + ft * 64 + c4);
    }
    __syncthreads();
    #pragma unroll 1
    for (int f = 0; f < 64; f += 4) {
      float4 a0 = *(const float4*)&sm.c.Ag[(tr * 4 + 0) * 68 + f];
      float4 a1 = *(const float4*)&sm.c.Ag[(tr * 4 + 1) * 68 + f];
      float4 a2 = *(const float4*)&sm.c.Ag[(tr * 4 + 2) * 68 + f];
      float4 a3 = *(const float4*)&sm.c.Ag[(tr * 4 + 3) * 68 + f];
      #pragma unroll
      for (int q = 0; q < 8; ++q) {
        float4 wv = *(const float4*)&sm.c.Ws[(q * 16 + tc) * 68 + f];
        acc[0][q] += a0.x * wv.x + a0.y * wv.y + a0.z * wv.z + a0.w * wv.w;
        acc[1][q] += a1.x * wv.x + a1.y * wv.y + a1.z * wv.z + a1.w * wv.w;
        acc[2][q] += a2.x * wv.x + a2.y * wv.y + a2.z * wv.z + a2.w * wv.w;
        acc[3][q] += a3.x * wv.x + a3.y * wv.y + a3.z * wv.z + a3.w * wv.w;
      }
    }
  }

  __syncthreads();
  #pragma unroll 1
  for (int r = 0; r < 4; ++r) {
    #pragma unroll
    for (int q = 0; q < 8; ++q)
      sm.L[tr * 136 + q * 16 + tc] = fmaxf(acc[r][q], 0.f);
    __syncthreads();
    #pragma unroll
    for (int k = 0; k < 2; ++k) {
      int lrow = 8 * k + (tid >> 5);
      int col = (tid & 31) * 4;
      float4 v = *(const float4*)&sm.L[lrow * 136 + col];
      int n = n0 + lrow * 4 + r;
      *(float4*)(out + (((size_t)(b * NN + n)) * TT + t) * FF + col) = v;
    }
    __syncthreads();
  }
}

// ---------------------------------------------------------------------------
extern "C" void kernel_launch(void* const* d_in, const int* in_sizes, int n_in,
                              void* d_out, int out_size, void* d_ws, size_t ws_size,
                              hipStream_t stream) {
  const float* x = (const float*)d_in[0];
  const float* phase = (const float*)d_in[1];
  const float* symadj = (const float*)d_in[2];
  const int* mask = (const int*)d_in[3];
  const float* Wt = (const float*)d_in[4];
  const float* Wl = (const float*)d_in[5];
  float* out = (float*)d_out;
  float* ws = (float*)d_ws;

  const size_t SX = (size_t)NB * NN * TT * FF;  // 3,932,160 floats
  float* xA = ws;
  float* xB = xA + SX;
  float* gateb = xB + SX;                        // NB*TT*NN floats
  float* Pw = gateb + (size_t)NB * TT * NN;      // NB*TT*NN*NN floats

  init_kernel<<<1024, 256, 0, stream>>>((const float4*)x, (float4*)xA,
                                        (float4*)xB, (int)(SX / 4));

  float* xc = xA;
  float* xn = xB;
  for (int it = 0; it < TT - 1; ++it) {
    gate_kernel<<<dim3(NN, NB), 128, 0, stream>>>(xc, Wl, gateb);
    score_kernel<<<dim3(4, TT - 1, NB), 256, 0, stream>>>(xc, phase, gateb, symadj, Pw, 0);
    pred_kernel<<<dim3(4, TT - 1, NB), 256, 0, stream>>>(xc, Pw, mask, xn, 0);
    float* tmp = xc; xc = xn; xn = tmp;
  }

  float* aggb = xn;  // free buffer
  score_kernel<<<dim3(4, TT, NB), 256, 0, stream>>>(xc, phase, nullptr, symadj, Pw, 1);
  pred_kernel<<<dim3(4, TT, NB), 256, 0, stream>>>(xc, Pw, nullptr, aggb, 1);
  theta_kernel<<<dim3(4, TT, NB), 256, 0, stream>>>(aggb, Wt, out);
}

// Round 6
// 4140.124 us; speedup vs baseline: 4.8305x; 1.0662x over previous
//
#include <hip/hip_runtime.h>
#include <math.h>

#define NN 256
#define TT 30
#define FF 128
#define NB 4

static constexpr float INV = 0.08838834764831845f; // 1/sqrt(128)

// ---------------------------------------------------------------------------
// init_kernel: copy x into both ping-pong buffers.
// ---------------------------------------------------------------------------
__global__ __launch_bounds__(256) void init_kernel(
    const float4* __restrict__ in, float4* __restrict__ a,
    float4* __restrict__ bb, int n4) {
  for (int i = blockIdx.x * 256 + threadIdx.x; i < n4; i += gridDim.x * 256) {
    float4 v = in[i];
    a[i] = v;
    bb[i] = v;
  }
}

// ---------------------------------------------------------------------------
// gate_kernel: per (b,n): A = softmax(X X^T * inv) over s; gate[b,t,n] = A@wl
// ---------------------------------------------------------------------------
__global__ __launch_bounds__(128) void gate_kernel(
    const float* __restrict__ x, const float* __restrict__ wlin,
    float* __restrict__ gate) {
  int n = blockIdx.x, b = blockIdx.y;
  __shared__ float Xs[TT * 132];
  __shared__ float A[TT * 33];
  __shared__ float wl[32];
  int tid = threadIdx.x;
  const float* xp = x + ((size_t)(b * NN + n)) * TT * FF;
  for (int idx = tid; idx < TT * 32; idx += 128) {
    int t = idx >> 5, q = idx & 31;
    *(float4*)&Xs[t * 132 + q * 4] = *(const float4*)&xp[t * 128 + q * 4];
  }
  if (tid < TT) wl[tid] = wlin[tid];
  __syncthreads();
  int t = tid >> 2, sg = tid & 3;
  if (t < TT) {
    float a[8];
    #pragma unroll
    for (int u = 0; u < 8; ++u) a[u] = 0.f;
    int smax = TT - sg * 8;  // 8,8,8,6
    #pragma unroll 1
    for (int q = 0; q < 32; ++q) {
      float4 av = *(const float4*)&Xs[t * 132 + q * 4];
      #pragma unroll
      for (int u = 0; u < 8; ++u) {
        if (u < smax) {
          float4 bv = *(const float4*)&Xs[(sg * 8 + u) * 132 + q * 4];
          a[u] += av.x * bv.x + av.y * bv.y + av.z * bv.z + av.w * bv.w;
        }
      }
    }
    #pragma unroll
    for (int u = 0; u < 8; ++u)
      if (u < smax) A[t * 33 + sg * 8 + u] = a[u] * INV;
  }
  __syncthreads();
  if (tid < TT) {
    float mx = -1e30f;
    #pragma unroll
    for (int s = 0; s < TT; ++s) mx = fmaxf(mx, A[tid * 33 + s]);
    float sum = 0.f, g = 0.f;
    #pragma unroll
    for (int s = 0; s < TT; ++s) {
      float e = expf(A[tid * 33 + s] - mx);
      sum += e;
      g += e * wl[s];
    }
    gate[((size_t)b * TT + tid) * NN + n] = g / sum;
  }
}

// ---------------------------------------------------------------------------
// score_kernel (64 rows x 256 cols per block, acc[4][16] in REGISTERS:
// f-loop unroll 1 to bound scheduler hoisting; epilogue loops fully
// unrolled so acc indexing stays static -> no scratch demotion):
// ---------------------------------------------------------------------------
__global__ __launch_bounds__(256) void score_kernel(
    const float* __restrict__ x, const float* __restrict__ phase,
    const float* __restrict__ gate, const float* __restrict__ symadj,
    float* __restrict__ P, int mode) {
  int ntile = blockIdx.x, t = blockIdx.y, b = blockIdx.z;
  int tq = t, tk = mode ? t : t + 1, pt = mode ? t : t + 1;
  __shared__ union {
    struct { float Xn[64 * 36]; float Xm[256 * 36]; } c;
    float L[16 * 264];
  } sm;
  int tid = threadIdx.x;
  int tr = tid >> 4, tc = tid & 15;
  int n0 = ntile * 64;
  float acc[4][16];
  #pragma unroll
  for (int r = 0; r < 4; ++r)
    #pragma unroll
    for (int j = 0; j < 16; ++j) acc[r][j] = 0.f;

  #pragma unroll 1
  for (int ftile = 0; ftile < 4; ++ftile) {
    __syncthreads();
    #pragma unroll 1
    for (int idx = tid; idx < 256 * 8; idx += 256) {
      int row = idx >> 3, q = idx & 7;
      *(float4*)&sm.c.Xm[row * 36 + q * 4] =
          *(const float4*)(x + (((size_t)(b * NN + row)) * TT + tk) * FF + ftile * 32 + q * 4);
    }
    {
      int row = tid >> 3, q = tid & 7;
      if (row < 64)
        *(float4*)&sm.c.Xn[row * 36 + q * 4] =
            *(const float4*)(x + (((size_t)(b * NN + n0 + row)) * TT + tq) * FF + ftile * 32 + q * 4);
      row += 32;
      if (row < 64)
        *(float4*)&sm.c.Xn[row * 36 + q * 4] =
            *(const float4*)(x + (((size_t)(b * NN + n0 + row)) * TT + tq) * FF + ftile * 32 + q * 4);
    }
    __syncthreads();
    #pragma unroll 1
    for (int f = 0; f < 32; f += 4) {
      float4 a0 = *(const float4*)&sm.c.Xn[(tr * 4 + 0) * 36 + f];
      float4 a1 = *(const float4*)&sm.c.Xn[(tr * 4 + 1) * 36 + f];
      float4 a2 = *(const float4*)&sm.c.Xn[(tr * 4 + 2) * 36 + f];
      float4 a3 = *(const float4*)&sm.c.Xn[(tr * 4 + 3) * 36 + f];
      #pragma unroll
      for (int j = 0; j < 16; ++j) {
        float4 bv = *(const float4*)&sm.c.Xm[(j * 16 + tc) * 36 + f];
        acc[0][j] += a0.x * bv.x + a0.y * bv.y + a0.z * bv.z + a0.w * bv.w;
        acc[1][j] += a1.x * bv.x + a1.y * bv.y + a1.z * bv.z + a1.w * bv.w;
        acc[2][j] += a2.x * bv.x + a2.y * bv.y + a2.z * bv.z + a2.w * bv.w;
        acc[3][j] += a3.x * bv.x + a3.y * bv.y + a3.z * bv.z + a3.w * bv.w;
      }
    }
  }

  // softmax over m per row; fold row-scale (gate or inv) into values
  float rowscale[4];
  #pragma unroll
  for (int r = 0; r < 4; ++r) {
    int n = n0 + tr * 4 + r;
    float mx = -1e30f;
    #pragma unroll
    for (int j = 0; j < 16; ++j) {
      acc[r][j] *= INV;
      mx = fmaxf(mx, acc[r][j]);
    }
    #pragma unroll
    for (int d = 1; d < 16; d <<= 1) mx = fmaxf(mx, __shfl_xor(mx, d));
    float sum = 0.f;
    #pragma unroll
    for (int j = 0; j < 16; ++j) {
      acc[r][j] = expf(acc[r][j] - mx);
      sum += acc[r][j];
    }
    #pragma unroll
    for (int d = 1; d < 16; d <<= 1) sum += __shfl_xor(sum, d);
    float rs = 1.f / sum;
    rowscale[r] = mode ? rs * INV : gate[((size_t)b * TT + pt) * NN + n] * rs;
  }

  // transposed epilogue through LDS: FULLY UNROLLED (static acc indexing)
  __syncthreads();
  #pragma unroll
  for (int r = 0; r < 4; ++r) {
    #pragma unroll
    for (int j = 0; j < 16; ++j)
      sm.L[tr * 264 + j * 16 + tc] = acc[r][j] * rowscale[r];
    __syncthreads();
    #pragma unroll
    for (int k = 0; k < 4; ++k) {
      int lrow = 4 * k + (tid >> 6);
      int col = (tid & 63) * 4;
      float4 v = *(const float4*)&sm.L[lrow * 264 + col];
      int n = n0 + lrow * 4 + r;
      float4 pv = *(const float4*)(phase + ((((size_t)(b * TT + pt)) * NN + n)) * NN + col);
      float4 o;
      o.x = v.x * pv.x; o.y = v.y * pv.y; o.z = v.z * pv.z; o.w = v.w * pv.w;
      if (mode) {
        float4 sv = *(const float4*)(symadj + (size_t)n * NN + col);
        o.x *= sv.x; o.y *= sv.y; o.z *= sv.z; o.w *= sv.w;
      }
      *(float4*)(P + (((size_t)(b * TT + t)) * NN + n) * NN + col) = o;
    }
    __syncthreads();
  }
}

// ---------------------------------------------------------------------------
// pred_kernel: out[n,f] = sum_m P[m,n] * x[b,m,t,f]   (P^T X)
// ---------------------------------------------------------------------------
__global__ __launch_bounds__(256) void pred_kernel(
    const float* __restrict__ x, const float* __restrict__ P,
    const int* __restrict__ mask, float* __restrict__ xout, int mode) {
  int ntile = blockIdx.x, t = blockIdx.y, b = blockIdx.z;
  __shared__ union {
    struct { float Pt[64 * 64]; float Xt[64 * 128]; } c;
    float L[16 * 136];
  } sm;
  int tid = threadIdx.x;
  int tr = tid >> 4, tc = tid & 15;
  int n0 = ntile * 64;
  float acc[4][8];
  #pragma unroll
  for (int r = 0; r < 4; ++r)
    #pragma unroll
    for (int q = 0; q < 8; ++q) acc[r][q] = 0.f;

  #pragma unroll 1
  for (int mt = 0; mt < 4; ++mt) {
    __syncthreads();
    #pragma unroll 1
    for (int idx = tid; idx < 64 * 16; idx += 256) {
      int row = idx >> 4, c4 = (idx & 15) * 4;
      *(float4*)&sm.c.Pt[row * 64 + c4] =
          *(const float4*)(P + (((size_t)(b * TT + t)) * NN + mt * 64 + row) * NN + n0 + c4);
    }
    #pragma unroll 1
    for (int idx = tid; idx < 64 * 32; idx += 256) {
      int row = idx >> 5, q = idx & 31;
      *(float4*)&sm.c.Xt[row * 128 + q * 4] =
          *(const float4*)(x + (((size_t)(b * NN + mt * 64 + row)) * TT + t) * FF + q * 4);
    }
    __syncthreads();
    #pragma unroll 1
    for (int i = 0; i < 64; ++i) {
      float4 pv = *(const float4*)&sm.c.Pt[i * 64 + tr * 4];
      #pragma unroll
      for (int q = 0; q < 8; ++q) {
        float xv = sm.c.Xt[i * 128 + q * 16 + tc];
        acc[0][q] += pv.x * xv;
        acc[1][q] += pv.y * xv;
        acc[2][q] += pv.z * xv;
        acc[3][q] += pv.w * xv;
      }
    }
  }

  __syncthreads();
  #pragma unroll
  for (int r = 0; r < 4; ++r) {
    #pragma unroll
    for (int q = 0; q < 8; ++q)
      sm.L[tr * 136 + q * 16 + tc] = acc[r][q];
    __syncthreads();
    #pragma unroll
    for (int k = 0; k < 2; ++k) {
      int lrow = 8 * k + (tid >> 5);
      int col = (tid & 31) * 4;
      float4 v = *(const float4*)&sm.L[lrow * 136 + col];
      int n = n0 + lrow * 4 + r;
      if (mode == 0) {
        int tw = t + 1;
        if (mask[n * TT + tw] == 0)
          *(float4*)(xout + (((size_t)(b * NN + n)) * TT + tw) * FF + col) = v;
      } else {
        *(float4*)(xout + (((size_t)(b * TT + t)) * NN + n) * FF + col) = v;
      }
    }
    __syncthreads();
  }
}

// ---------------------------------------------------------------------------
// theta_kernel: out[b,n,t,o] = relu(sum_f agg[b,t,n,f] * Wt[o,f])
// ---------------------------------------------------------------------------
__global__ __launch_bounds__(256) void theta_kernel(
    const float* __restrict__ agg, const float* __restrict__ Wt,
    float* __restrict__ out) {
  int ntile = blockIdx.x, t = blockIdx.y, b = blockIdx.z;
  __shared__ union {
    struct { float Ag[64 * 68]; float Ws[128 * 68]; } c;
    float L[16 * 136];
  } sm;
  int tid = threadIdx.x;
  int tr = tid >> 4, tc = tid & 15;
  int n0 = ntile * 64;
  float acc[4][8];
  #pragma unroll
  for (int r = 0; r < 4; ++r)
    #pragma unroll
    for (int q = 0; q < 8; ++q) acc[r][q] = 0.f;

  #pragma unroll 1
  for (int ft = 0; ft < 2; ++ft) {
    __syncthreads();
    #pragma unroll 1
    for (int idx = tid; idx < 64 * 16; idx += 256) {
      int row = idx >> 4, c4 = (idx & 15) * 4;
      *(float4*)&sm.c.Ag[row * 68 + c4] =
          *(const float4*)(agg + (((size_t)(b * TT + t)) * NN + n0 + row) * FF + ft * 64 + c4);
    }
    #pragma unroll 1
    for (int idx = tid; idx < 128 * 16; idx += 256) {
      int row = idx >> 4, c4 = (idx & 15) * 4;
      *(float4*)&sm.c.Ws[row * 68 + c4] =
          *(const float4*)(Wt + (size_t)row * FF + ft * 64 + c4);
    }
    __syncthreads();
    #pragma unroll 1
    for (int f = 0; f < 64; f += 4) {
      float4 a0 = *(const float4*)&sm.c.Ag[(tr * 4 + 0) * 68 + f];
      float4 a1 = *(const float4*)&sm.c.Ag[(tr * 4 + 1) * 68 + f];
      float4 a2 = *(const float4*)&sm.c.Ag[(tr * 4 + 2) * 68 + f];
      float4 a3 = *(const float4*)&sm.c.Ag[(tr * 4 + 3) * 68 + f];
      #pragma unroll
      for (int q = 0; q < 8; ++q) {
        float4 wv = *(const float4*)&sm.c.Ws[(q * 16 + tc) * 68 + f];
        acc[0][q] += a0.x * wv.x + a0.y * wv.y + a0.z * wv.z + a0.w * wv.w;
        acc[1][q] += a1.x * wv.x + a1.y * wv.y + a1.z * wv.z + a1.w * wv.w;
        acc[2][q] += a2.x * wv.x + a2.y * wv.y + a2.z * wv.z + a2.w * wv.w;
        acc[3][q] += a3.x * wv.x + a3.y * wv.y + a3.z * wv.z + a3.w * wv.w;
      }
    }
  }

  __syncthreads();
  #pragma unroll
  for (int r = 0; r < 4; ++r) {
    #pragma unroll
    for (int q = 0; q < 8; ++q)
      sm.L[tr * 136 + q * 16 + tc] = fmaxf(acc[r][q], 0.f);
    __syncthreads();
    #pragma unroll
    for (int k = 0; k < 2; ++k) {
      int lrow = 8 * k + (tid >> 5);
      int col = (tid & 31) * 4;
      float4 v = *(const float4*)&sm.L[lrow * 136 + col];
      int n = n0 + lrow * 4 + r;
      *(float4*)(out + (((size_t)(b * NN + n)) * TT + t) * FF + col) = v;
    }
    __syncthreads();
  }
}

// ---------------------------------------------------------------------------
extern "C" void kernel_launch(void* const* d_in, const int* in_sizes, int n_in,
                              void* d_out, int out_size, void* d_ws, size_t ws_size,
                              hipStream_t stream) {
  const float* x = (const float*)d_in[0];
  const float* phase = (const float*)d_in[1];
  const float* symadj = (const float*)d_in[2];
  const int* mask = (const int*)d_in[3];
  const float* Wt = (const float*)d_in[4];
  const float* Wl = (const float*)d_in[5];
  float* out = (float*)d_out;
  float* ws = (float*)d_ws;

  const size_t SX = (size_t)NB * NN * TT * FF;  // 3,932,160 floats
  float* xA = ws;
  float* xB = xA + SX;
  float* gateb = xB + SX;                        // NB*TT*NN floats
  float* Pw = gateb + (size_t)NB * TT * NN;      // NB*TT*NN*NN floats

  init_kernel<<<1024, 256, 0, stream>>>((const float4*)x, (float4*)xA,
                                        (float4*)xB, (int)(SX / 4));

  float* xc = xA;
  float* xn = xB;
  for (int it = 0; it < TT - 1; ++it) {
    gate_kernel<<<dim3(NN, NB), 128, 0, stream>>>(xc, Wl, gateb);
    score_kernel<<<dim3(4, TT - 1, NB), 256, 0, stream>>>(xc, phase, gateb, symadj, Pw, 0);
    pred_kernel<<<dim3(4, TT - 1, NB), 256, 0, stream>>>(xc, Pw, mask, xn, 0);
    float* tmp = xc; xc = xn; xn = tmp;
  }

  float* aggb = xn;  // free buffer
  score_kernel<<<dim3(4, TT, NB), 256, 0, stream>>>(xc, phase, nullptr, symadj, Pw, 1);
  pred_kernel<<<dim3(4, TT, NB), 256, 0, stream>>>(xc, Pw, nullptr, aggb, 1);
  theta_kernel<<<dim3(4, TT, NB), 256, 0, stream>>>(aggb, Wt, out);
}